// Round 1
// baseline (523.954 us; speedup 1.0000x reference)
//
#include <hip/hip_runtime.h>
#include <math.h>

// Problem constants
static const int B_  = 4;
static const int CE_ = 128;
static const int CD_ = 256;
static const int HE_ = 256;   // = WE
static const int HD_ = 128;   // = WD
static const int N_  = 16;
#define PLANE  65536          // HE*WE = 256*256
#define DPLANE 16384          // HD*WD = 128*128
#define UPSCALE (127.0f/255.0f)

// ---------------------------------------------------------------------------
// K1: enc per-pixel channel stats: max_c, mean_c, proj_c(sw1_e)+sb1_e
// grid = B*HE blocks (one per (b,row)), 256 threads (one per col)
// writes stats channels [b][0..2][h][w]
// ---------------------------------------------------------------------------
__global__ __launch_bounds__(256) void k_enc_pix(
    const float* __restrict__ x, const float* __restrict__ sw1,
    const float* __restrict__ sb1, float* __restrict__ stats) {
  int bh = blockIdx.x;
  int b = bh >> 8, h = bh & 255;
  int w = threadIdx.x;
  __shared__ float sw[CE_];
  if (threadIdx.x < CE_) sw[threadIdx.x] = sw1[threadIdx.x];
  __syncthreads();
  const float* base = x + (((size_t)b * CE_) * HE_ + h) * (size_t)HE_ + w;
  float mx = -INFINITY, sm = 0.f, pj = 0.f;
#pragma unroll 4
  for (int c = 0; c < CE_; ++c) {
    float v = base[(size_t)c * PLANE];
    mx = fmaxf(mx, v);
    sm += v;
    pj = fmaf(v, sw[c], pj);
  }
  size_t o = (((size_t)b * 6) * HE_ + h) * (size_t)HE_ + w;
  stats[o] = mx;
  stats[o + (size_t)PLANE] = sm * (1.f / CE_);
  stats[o + 2 * (size_t)PLANE] = pj + sb1[0];
}

// ---------------------------------------------------------------------------
// K2: enc per-channel spatial stats: mean_hw, max_hw per (b,c)
// grid = B*CE blocks, 256 threads; float4 loads
// ---------------------------------------------------------------------------
__global__ __launch_bounds__(256) void k_enc_chan(
    const float* __restrict__ x, float* __restrict__ av, float* __restrict__ mx) {
  int bc = blockIdx.x;
  const float4* p = (const float4*)(x + (size_t)bc * PLANE);
  float sm = 0.f, m = -INFINITY;
  for (int i = threadIdx.x; i < PLANE / 4; i += 256) {
    float4 v = p[i];
    sm += (v.x + v.y) + (v.z + v.w);
    m = fmaxf(m, fmaxf(fmaxf(v.x, v.y), fmaxf(v.z, v.w)));
  }
  __shared__ float ss[256], sx[256];
  int t = threadIdx.x;
  ss[t] = sm; sx[t] = m;
  __syncthreads();
  for (int s = 128; s > 0; s >>= 1) {
    if (t < s) { ss[t] += ss[t + s]; sx[t] = fmaxf(sx[t], sx[t + s]); }
    __syncthreads();
  }
  if (t == 0) { av[bc] = ss[0] * (1.f / PLANE); mx[bc] = sx[0]; }
}

// ---------------------------------------------------------------------------
// K3: dec per-pixel channel stats on the fly (bilinear up2x align_corners + relu)
// grid = B*256 blocks (b,out_row), 256 threads (out col)
// writes stats channels [b][3..5][h][w]
// ---------------------------------------------------------------------------
__global__ __launch_bounds__(256) void k_dec_pix(
    const float* __restrict__ x, const float* __restrict__ sw1,
    const float* __restrict__ sb1, float* __restrict__ stats) {
  int bh = blockIdx.x;
  int b = bh >> 8, h = bh & 255;
  int w = threadIdx.x;
  __shared__ float sw[CD_];
  sw[threadIdx.x] = sw1[threadIdx.x];
  __syncthreads();
  float ph = (float)h * UPSCALE;
  int ih0 = (int)ph; float wh = ph - (float)ih0;
  int ih1 = min(ih0 + 1, HD_ - 1);
  float pw = (float)w * UPSCALE;
  int iw0 = (int)pw; float ww = pw - (float)iw0;
  int iw1 = min(iw0 + 1, HD_ - 1);
  float w00 = (1.f - wh) * (1.f - ww), w01 = (1.f - wh) * ww;
  float w10 = wh * (1.f - ww),        w11 = wh * ww;
  const float* xb = x + (size_t)b * CD_ * DPLANE;
  int o00 = ih0 * HD_ + iw0, o01 = ih0 * HD_ + iw1;
  int o10 = ih1 * HD_ + iw0, o11 = ih1 * HD_ + iw1;
  float mx = -INFINITY, sm = 0.f, pj = 0.f;
#pragma unroll 2
  for (int c = 0; c < CD_; ++c) {
    const float* pc = xb + (size_t)c * DPLANE;
    float v = w00 * pc[o00] + w01 * pc[o01] + w10 * pc[o10] + w11 * pc[o11];
    v = fmaxf(v, 0.f);
    mx = fmaxf(mx, v);
    sm += v;
    pj = fmaf(v, sw[c], pj);
  }
  size_t o = (((size_t)b * 6 + 3) * HE_ + h) * (size_t)HE_ + w;
  stats[o] = mx;
  stats[o + (size_t)PLANE] = sm * (1.f / CD_);
  stats[o + 2 * (size_t)PLANE] = pj + sb1[0];
}

// ---------------------------------------------------------------------------
// K4: dec per-channel spatial stats over the virtual upsampled+relu plane
// grid = B*CD blocks (one per (b,c)), 256 threads (one per out col)
// ---------------------------------------------------------------------------
__global__ __launch_bounds__(256) void k_dec_chan(
    const float* __restrict__ x, float* __restrict__ av, float* __restrict__ mx) {
  int bc = blockIdx.x;
  const float* p = x + (size_t)bc * DPLANE;
  int t = threadIdx.x;
  float pw = (float)t * UPSCALE;
  int iw0 = (int)pw; float ww = pw - (float)iw0;
  int iw1 = min(iw0 + 1, HD_ - 1);
  float sm = 0.f, m = -INFINITY;
  for (int h = 0; h < 256; ++h) {
    float ph = (float)h * UPSCALE;
    int ih0 = (int)ph; float wh = ph - (float)ih0;
    int ih1 = min(ih0 + 1, HD_ - 1);
    const float* r0 = p + ih0 * HD_;
    const float* r1 = p + ih1 * HD_;
    float top = r0[iw0] * (1.f - ww) + r0[iw1] * ww;
    float bot = r1[iw0] * (1.f - ww) + r1[iw1] * ww;
    float v = fmaxf((1.f - wh) * top + wh * bot, 0.f);
    sm += v;
    m = fmaxf(m, v);
  }
  __shared__ float ss[256], sx[256];
  ss[t] = sm; sx[t] = m;
  __syncthreads();
  for (int s = 128; s > 0; s >>= 1) {
    if (t < s) { ss[t] += ss[t + s]; sx[t] = fmaxf(sx[t], sx[t + s]); }
    __syncthreads();
  }
  if (t == 0) { av[bc] = ss[0] * (1.f / PLANE); mx[bc] = sx[0]; }
}

// ---------------------------------------------------------------------------
// K5: spatial attention: spat = sigmoid(conv7(enc_stats, sw2_e)+sb2_e +
//                                       conv7(dec_stats, sw2_d)+sb2_d)
// grid = B*256 blocks (b,row), 256 threads (col)
// ---------------------------------------------------------------------------
__global__ __launch_bounds__(256) void k_sag(
    const float* __restrict__ stats, const float* __restrict__ we,
    const float* __restrict__ be, const float* __restrict__ wd,
    const float* __restrict__ bd, float* __restrict__ spat) {
  int bh = blockIdx.x;
  int b = bh >> 8, h = bh & 255;
  int w = threadIdx.x;
  __shared__ float swE[147], swD[147];
  if (threadIdx.x < 147) { swE[threadIdx.x] = we[threadIdx.x]; swD[threadIdx.x] = wd[threadIdx.x]; }
  __syncthreads();
  float acc = be[0] + bd[0];
  const float* sb = stats + ((size_t)b * 6) * PLANE;
#pragma unroll
  for (int ic = 0; ic < 3; ++ic) {
    const float* pe = sb + (size_t)ic * PLANE;
    const float* pd = sb + (size_t)(ic + 3) * PLANE;
#pragma unroll
    for (int ky = 0; ky < 7; ++ky) {
      int y = h + ky - 3;
      if ((unsigned)y >= 256u) continue;
      const float* rowE = pe + y * 256;
      const float* rowD = pd + y * 256;
#pragma unroll
      for (int kx = 0; kx < 7; ++kx) {
        int xw = w + kx - 3;
        if ((unsigned)xw >= 256u) continue;
        float we_ = swE[ic * 49 + ky * 7 + kx];
        float wd_ = swD[ic * 49 + ky * 7 + kx];
        acc = fmaf(rowE[xw], we_, acc);
        acc = fmaf(rowD[xw], wd_, acc);
      }
    }
  }
  spat[(size_t)b * PLANE + h * 256 + w] = 1.f / (1.f + __expf(-acc));
}

// ---------------------------------------------------------------------------
// K6: channel attention (tiny): ce+cd -> MLP -> sigmoid -> ch[b*128+o]
// 1 block, 512 threads
// ---------------------------------------------------------------------------
__global__ __launch_bounds__(512) void k_cag(
    const float* __restrict__ eav, const float* __restrict__ emx,
    const float* __restrict__ dav, const float* __restrict__ dmx,
    const float* __restrict__ cw_ea, const float* __restrict__ cb_ea,
    const float* __restrict__ cw_em, const float* __restrict__ cb_em,
    const float* __restrict__ cw_da, const float* __restrict__ cb_da,
    const float* __restrict__ cw_dm, const float* __restrict__ cb_dm,
    const float* __restrict__ cw_f, const float* __restrict__ cb_f,
    float* __restrict__ ch) {
  __shared__ float scd[B_ * N_];
  int t = threadIdx.x;
  if (t < B_ * N_) {
    int b = t >> 4, n = t & 15;
    float s = cb_ea[n] + cb_em[n] + cb_da[n] + cb_dm[n];
    for (int c = 0; c < CE_; ++c)
      s += eav[b * CE_ + c] * cw_ea[n * CE_ + c] + emx[b * CE_ + c] * cw_em[n * CE_ + c];
    for (int c = 0; c < CD_; ++c)
      s += dav[b * CD_ + c] * cw_da[n * CD_ + c] + dmx[b * CD_ + c] * cw_dm[n * CD_ + c];
    scd[t] = s;
  }
  __syncthreads();
  int b = t >> 7, o = t & 127;
  float s = cb_f[o];
#pragma unroll
  for (int n = 0; n < N_; ++n) s += scd[b * N_ + n] * cw_f[o * N_ + n];
  ch[t] = 1.f / (1.f + __expf(-s));
}

// ---------------------------------------------------------------------------
// K7: final gate: out = x_enc * spat[b,hw] * ch[b,c]   (float4)
// ---------------------------------------------------------------------------
__global__ __launch_bounds__(256) void k_final(
    const float* __restrict__ x, const float* __restrict__ spat,
    const float* __restrict__ ch, float* __restrict__ out) {
  size_t i4 = (size_t)blockIdx.x * 256 + threadIdx.x;
  size_t e = i4 * 4;
  int b = (int)(e >> 23);          // CE*PLANE = 2^23
  int c = (int)((e >> 16) & 127);  // PLANE = 2^16
  int p = (int)(e & 65535);
  float4 xv = ((const float4*)x)[i4];
  float4 sv = *(const float4*)(spat + ((size_t)b << 16) + p);
  float cv = ch[(b << 7) | c];
  float4 o;
  o.x = xv.x * sv.x * cv;
  o.y = xv.y * sv.y * cv;
  o.z = xv.z * sv.z * cv;
  o.w = xv.w * sv.w * cv;
  ((float4*)out)[i4] = o;
}

// ---------------------------------------------------------------------------
extern "C" void kernel_launch(void* const* d_in, const int* in_sizes, int n_in,
                              void* d_out, int out_size, void* d_ws, size_t ws_size,
                              hipStream_t stream) {
  const float* x_enc = (const float*)d_in[0];
  const float* x_dec = (const float*)d_in[1];
  const float* cw_ea = (const float*)d_in[2];
  const float* cb_ea = (const float*)d_in[3];
  const float* cw_em = (const float*)d_in[4];
  const float* cb_em = (const float*)d_in[5];
  const float* cw_da = (const float*)d_in[6];
  const float* cb_da = (const float*)d_in[7];
  const float* cw_dm = (const float*)d_in[8];
  const float* cb_dm = (const float*)d_in[9];
  const float* cw_f  = (const float*)d_in[10];
  const float* cb_f  = (const float*)d_in[11];
  const float* sw1_e = (const float*)d_in[12];
  const float* sb1_e = (const float*)d_in[13];
  const float* sw2_e = (const float*)d_in[14];
  const float* sb2_e = (const float*)d_in[15];
  const float* sw1_d = (const float*)d_in[16];
  const float* sb1_d = (const float*)d_in[17];
  const float* sw2_d = (const float*)d_in[18];
  const float* sb2_d = (const float*)d_in[19];
  float* out = (float*)d_out;

  // workspace layout (floats)
  float* ws    = (float*)d_ws;
  float* stats = ws;                       // B*6*PLANE = 1,572,864
  float* spat  = ws + 1572864;             // B*PLANE   =   262,144
  float* eav   = ws + 1835008;             // B*CE = 512
  float* emx   = eav + 512;                // 512
  float* dav   = emx + 512;                // B*CD = 1024
  float* dmx   = dav + 1024;               // 1024
  float* chn   = dmx + 1024;               // B*CE = 512

  k_enc_pix <<<B_ * HE_, 256, 0, stream>>>(x_enc, sw1_e, sb1_e, stats);
  k_enc_chan<<<B_ * CE_, 256, 0, stream>>>(x_enc, eav, emx);
  k_dec_pix <<<B_ * HE_, 256, 0, stream>>>(x_dec, sw1_d, sb1_d, stats);
  k_dec_chan<<<B_ * CD_, 256, 0, stream>>>(x_dec, dav, dmx);
  k_sag     <<<B_ * HE_, 256, 0, stream>>>(stats, sw2_e, sb2_e, sw2_d, sb2_d, spat);
  k_cag     <<<1, 512, 0, stream>>>(eav, emx, dav, dmx,
                                    cw_ea, cb_ea, cw_em, cb_em,
                                    cw_da, cb_da, cw_dm, cb_dm,
                                    cw_f, cb_f, chn);
  k_final   <<<(out_size / 4 + 255) / 256, 256, 0, stream>>>(x_enc, spat, chn, out);
}